// Round 3
// baseline (650.684 us; speedup 1.0000x reference)
//
#include <hip/hip_runtime.h>

// Problem constants (match the JAX reference).
constexpr int Zd = 224;
constexpr int Yd = 512;
constexpr int Xd = 512;
constexpr int Pd = 15;          // spectral predictors
constexpr int WDIM = Pd + 4;    // 19 weights per band
constexpr float MAXV = 32767.0f;   // 2^15 - 1
constexpr float MINV = -32768.0f;  // -2^15

constexpr int NCHUNK = 4;            // z-chunks
constexpr int CHUNK  = Zd / NCHUNK;  // 56 bands per chunk

typedef float v2f __attribute__((ext_vector_type(2)));

// pred[z,y,x] = clip( cn*north + cw*west + cnw*nw
//                     + sum_{k=0..14} w[4+k]*image[z-15+k,y,x] )
// with cn = w0 + w3/3 etc. (folding the "fourth" predictor).
//
// Rolling-window kernel, r3: thread owns (y, x..x+1) — HALF the previous
// footprint. The 15-band register window drops 60 -> 30 VGPRs, total live
// ~55, which fits the 64-VGPR cap of __launch_bounds__(256, 8):
// 8 waves/SIMD instead of 4. r0-r2 showed prefetch/nt/shfl all neutral at
// 4 waves/SIMD -> the binding constraint is resident-wave latency hiding,
// not per-wave scheduling. Traffic is unchanged (wave = 64 lanes x 8 B =
// 512 B contiguous loads/stores); per-wave VALU halves; in-flight vmem
// doubles.
//
// Kept from r2 (neutral but not harmful, and they reduce vmem/regs):
//  - depth-1 register prefetch of band z+1;
//  - left-edge west[0]/nw[0] via __shfl_up(lane-1), global dword only for
//    each wave's lane 0 (x-boundary), predicated;
//  - nontemporal float2 stores for the pure-streaming outputs.
__global__ __launch_bounds__(256, 8) void spec_pred_roll(
    const float* __restrict__ image,
    const float* __restrict__ weights,
    float* __restrict__ preds,
    float* __restrict__ resids)
{
    const int y  = blockIdx.y;                 // one y-row per block
    const int x  = threadIdx.x * 2;            // 256 threads cover X=512
    const int z0 = blockIdx.x * CHUNK;

    const bool edge    = ((threadIdx.x & 63) == 0);  // wave's lane 0
    const bool edge_ld = edge && (x > 0);            // needs global left dword
    const bool has_n   = (y > 0);

    const long long YX = (long long)Yd * Xd;
    long long o = (long long)z0 * YX + (long long)y * Xd + x;  // marching offset

    // Rolling history: h[k] holds image[z-15+k, y, x..x+1].  30 VGPRs.
    v2f h[Pd];
#pragma unroll
    for (int k = 0; k < Pd; ++k) {
        const int zk = z0 - Pd + k;            // uniform branch (z0 uniform)
        h[k] = (zk >= 0) ? *(const v2f*)(image + (long long)(zk - z0) * YX + o)
                         : (v2f){0.f, 0.f};
    }

    // Prefetch band z0 (self + north + wave-boundary left scalars).
    v2f   self_n  = *(const v2f*)(image + o);
    v2f   north_n = {0.f, 0.f};
    float sl_n = 0.f, nl_n = 0.f;
    if (has_n) north_n = *(const v2f*)(image + o - Xd);
    if (edge_ld) {
        sl_n = image[o - 1];
        if (has_n) nl_n = image[o - Xd - 1];
    }

    for (int i = 0; i < CHUNK; ++i) {
        // Consume the prefetched band.
        const v2f   self  = self_n;
        const v2f   north = north_n;
        const float sl_e  = sl_n;
        const float nl_e  = nl_n;

        // Depth-1 prefetch of band z+1: issue NOW, latency hides under the
        // FMA chain (and under the other 7 waves on this SIMD).
        if (i + 1 < CHUNK) {
            const long long on = o + YX;
            self_n = *(const v2f*)(image + on);
            if (has_n) north_n = *(const v2f*)(image + on - Xd);
            if (edge_ld) {
                sl_n = image[on - 1];
                if (has_n) nl_n = image[on - Xd - 1];
            }
        }

        // Per-band weights: wave-uniform address -> scalar loads.
        const int z = z0 + i;
        const float* wr = weights + z * WDIM;
        const float w3  = wr[3] * (1.0f / 3.0f);
        const float cn  = wr[0] + w3;
        const float cw  = wr[1] + w3;
        const float cnw = wr[2] + w3;

        // Left neighbors from lane-1 (wave is x-contiguous); wave-boundary
        // lane 0 uses the prefetched global dword (x==0 lanes keep 0.0).
        float sl = __shfl_up(self[1], 1);
        float nl = __shfl_up(north[1], 1);
        if (edge) { sl = sl_e; nl = nl_e; }

        const v2f west = {sl, self[0]};
        const v2f nwv  = {nl, north[0]};

        v2f p = cn * north + cw * west + cnw * nwv;

        // Spectral predictors from the register window (bands z-15 .. z-1).
#pragma unroll
        for (int k = 0; k < Pd; ++k) {
            p += wr[4 + k] * h[k];
        }

        p[0] = fminf(fmaxf(p[0], MINV), MAXV);
        p[1] = fminf(fmaxf(p[1], MINV), MAXV);

        const v2f r = self - p;

        // Streaming outputs: nontemporal -> keep L2 for the image reads.
        __builtin_nontemporal_store(p, (v2f*)(preds + o));
        __builtin_nontemporal_store(r, (v2f*)(resids + o));

        // Advance the window (constant indices -> stays in registers).
#pragma unroll
        for (int k = 0; k < Pd - 1; ++k) h[k] = h[k + 1];
        h[Pd - 1] = self;

        o += YX;
    }
}

extern "C" void kernel_launch(void* const* d_in, const int* in_sizes, int n_in,
                              void* d_out, int out_size, void* d_ws, size_t ws_size,
                              hipStream_t stream) {
    const float* image   = (const float*)d_in[0];
    const float* weights = (const float*)d_in[1];
    // d_in[2] (local_sums) only feeds the discarded carry — unused.

    float* preds  = (float*)d_out;
    float* resids = (float*)d_out + (long long)Zd * Yd * Xd;

    dim3 block(256, 1, 1);                // 256 threads = one full X row (f2/thread)
    dim3 grid(NCHUNK, Yd, 1);             // 4 z-chunks x 512 y-rows = 2048 blocks
    spec_pred_roll<<<grid, block, 0, stream>>>(image, weights, preds, resids);
}